// Round 9
// baseline (384.625 us; speedup 1.0000x reference)
//
#include <hip/hip_runtime.h>
#include <stdint.h>

// ---------------------------------------------------------------------------
// RPN loss: IoU>0.7 matching + argmax fix + exact JAX threefry sampling
// (partitionable PRNG path) + smooth-L1 + BCE, all on device.
// R1-R6: algorithmic fixes (2785 -> 347us). R7: lane-owns-column iou,
// binid cache (347->314us). R8: launch-count collapse 31 -> 12:
//   - k_iou absorbs init+fix (per-block partials + last-block reduce/fixup)
//   - k_scan_emit: decoupled-lookback fused cnt/scan/emit + block511 setup
//   - k_pos: entire pos chain in one 1024-thread block (LDS resident)
//   - k_hist3: all 3 neg hists+binids in one kernel (arrays pre-zeroed by
//     one upfront hipMemsetAsync -> no cross-kernel clears anywhere)
//   - k_selscan: select(m) + last-block does scanloc(m+1)
//   - k_loss: neg free-index remap via binary search on T[q]-q > e
// ---------------------------------------------------------------------------

#define N_PRED   131072
#define NBOXK    64
#define NM_TOT   8388608u          // N_PRED * NBOXK
#define TCAP     65536
#define NBINS    8192
#define BINSHIFT 19                // key >> 19 -> 13-bit bin
#define SLOTCAP  3072
#define MAXSLOT  192
#define HCAP     2048              // per-block LDS hit buffer (gather)
#define CBLK     512               // iou/scan blocks
#define POSCAP   32                // per-bin candidate cap in k_pos

typedef unsigned long long ull;

struct WS {
  // ---- zeroed by hipMemsetAsync at the head of every launch ----
  uint32_t iouDone;
  uint32_t selDone[2];
  uint32_t zpad;
  ull      lookback[CBLK];          // packed state<<32 | value
  uint32_t hist3[3][NBINS];         // per-backward-round neg histograms
  // ---- end zero region ----
  uint32_t P, M, n_pos, n_neg;
  uint32_t R[2];                    // shuffle rounds per chain (0=pos,1=neg)
  uint32_t S[2];
  uint32_t kcnt[2];
  uint32_t sub[2][3][2];            // per-round subkeys
  uint32_t nslots;
  ull      colBestBlk[CBLK][NBOXK]; // per-block iou argmax partials
  ull      maskWords[N_PRED];
  uint32_t T[TCAP];
  uint32_t tgt[2][256];
  int32_t  binslot[NBINS];
  int32_t  tslot[256];
  uint32_t tlocal[256];
  uint32_t slotCnt[MAXSLOT];
  ull      slotBuf[MAXSLOT][SLOTCAP];
  uint16_t binid3[3][NM_TOT];       // 50MB bin-id cache (ws is 256MB)
};
#define ZBYTES (16 + CBLK*8 + 3*NBINS*4)

// Threefry-2x32-20, matches JAX reference implementation exactly.
__device__ __forceinline__ void tf2(uint32_t k0, uint32_t k1,
                                    uint32_t& x0, uint32_t& x1) {
  uint32_t ks[3] = {k0, k1, k0 ^ k1 ^ 0x1BD11BDAu};
  const uint32_t R0[4] = {13u, 15u, 26u, 6u};
  const uint32_t R1[4] = {17u, 29u, 16u, 24u};
  x0 += ks[0]; x1 += ks[1];
#pragma unroll
  for (int i = 0; i < 5; ++i) {
    const uint32_t* rr = (i & 1) ? R1 : R0;
#pragma unroll
    for (int j = 0; j < 4; ++j) {
      x0 += x1;
      x1 = (x1 << rr[j]) | (x1 >> (32u - rr[j]));
      x1 ^= x0;
    }
    x0 += ks[(i + 1) % 3];
    x1 += ks[(i + 2) % 3] + (uint32_t)(i + 1);
  }
}

__device__ __forceinline__ uint32_t tf_bits(uint32_t k0, uint32_t k1, uint32_t p) {
  uint32_t a = 0u, b = p;
  tf2(k0, k1, a, b);
  return a ^ b;
}

__device__ __forceinline__ ull umax64(ull a, ull b) { return a > b ? a : b; }

// IoU mask + per-column argmax; per-block partials; last block reduces and
// applies the "need" fixup. Lane l owns column l (zero shuffles).
__global__ __launch_bounds__(256) void k_iou(const float4* __restrict__ pred,
                                             const float4* __restrict__ tgtb,
                                             WS* ws) {
  __shared__ float4 sp[256];
  __shared__ ull cb[NBOXK];
  __shared__ ull red[4][NBOXK];
  __shared__ uint32_t lastF;
  int t = threadIdx.x;
  int lane = t & 63;
  int w = t >> 6;
  int rowBase = blockIdx.x * 256;
  sp[t] = pred[rowBase + t];
  if (t < NBOXK) cb[t] = 0ull;
  float4 tb = tgtb[lane];
  float ta = __fmul_rn(__fsub_rn(tb.z, tb.x), __fsub_rn(tb.w, tb.y));
  __syncthreads();
  ull myWord = 0ull;
  float bestI = -1.0f;
  uint32_t bestRow = 0u;
  int wbase = w * 64;
  for (int r = 0; r < 64; ++r) {
    float4 p = sp[wbase + r];
    float pa = __fmul_rn(__fsub_rn(p.z, p.x), __fsub_rn(p.w, p.y));
    float ltx = fmaxf(p.x, tb.x), lty = fmaxf(p.y, tb.y);
    float rbx = fminf(p.z, tb.z), rby = fminf(p.w, tb.w);
    float wx = fmaxf(__fsub_rn(rbx, ltx), 0.0f);
    float wy = fmaxf(__fsub_rn(rby, lty), 0.0f);
    float inter = __fmul_rn(wx, wy);
    float uni = __fsub_rn(__fadd_rn(pa, ta), inter);
    float iou = __fdiv_rn(inter, uni);
    ull bal = __ballot(iou > 0.7f);
    if (lane == r) myWord = bal;
    if (iou > bestI) { bestI = iou; bestRow = (uint32_t)(rowBase + wbase + r); }
  }
  ws->maskWords[rowBase + wbase + lane] = myWord;
  ull pk = ((ull)__float_as_uint(bestI) << 32) | (ull)(~bestRow);
  atomicMax(&cb[lane], pk);
  __syncthreads();
  if (t < NBOXK) ws->colBestBlk[blockIdx.x][t] = cb[t];
  __threadfence();
  if (t == 0)
    lastF = (atomicAdd(&ws->iouDone, 1u) == (uint32_t)(gridDim.x - 1)) ? 1u : 0u;
  __syncthreads();
  if (lastF) {
    int c = t & 63, q = t >> 6;
    ull best = 0ull;
    for (int b = q; b < CBLK; b += 4) best = umax64(best, ws->colBestBlk[b][c]);
    red[q][c] = best;
    __syncthreads();
    if (t < NBOXK) {
      ull m_ = umax64(umax64(red[0][t], red[1][t]), umax64(red[2][t], red[3][t]));
      float bi = __uint_as_float((uint32_t)(m_ >> 32));
      if (!(bi > 0.7f)) {
        uint32_t row = ~(uint32_t)(m_ & 0xFFFFFFFFu);
        atomicOr(&ws->maskWords[row], 1ull << t);
      }
    }
  }
}

// Fused count + global scan (decoupled lookback) + ordered emit; block 511
// does the scalar/PRNG setup. All 512 blocks co-resident -> lookback safe.
__global__ __launch_bounds__(256) void k_scan_emit(WS* ws) {
  __shared__ uint32_t sm[256];
  __shared__ uint32_t exclS;
  int t = threadIdx.x, b = blockIdx.x;
  int row = b * 256 + t;
  ull w = ws->maskWords[row];
  uint32_t c = (uint32_t)__popcll(w);
  sm[t] = c;
  __syncthreads();
  for (int off = 1; off < 256; off <<= 1) {
    uint32_t add = (t >= off) ? sm[t - off] : 0u;
    __syncthreads();
    sm[t] += add;
    __syncthreads();
  }
  uint32_t mySum = sm[255];
  if (t == 0) {
    uint32_t excl = 0u;
    if (b == 0) {
      atomicExch(&ws->lookback[0], (2ull << 32) | (ull)mySum);
    } else {
      atomicExch(&ws->lookback[b], (1ull << 32) | (ull)mySum);
      int i = b - 1;
      uint32_t run = 0u;
      while (true) {
        ull x = atomicAdd(&ws->lookback[i], 0ull);
        uint32_t st = (uint32_t)(x >> 32);
        if (st == 0u) continue;
        run += (uint32_t)x;
        if (st == 2u) break;
        --i;
      }
      excl = run;
      atomicExch(&ws->lookback[b], (2ull << 32) | (ull)(excl + mySum));
    }
    exclS = excl;
  }
  __syncthreads();
  uint32_t off0 = exclS + sm[t] - c;
  while (w) {
    int bit = __ffsll((long long)w) - 1;
    w &= (w - 1);
    if (off0 < TCAP) ws->T[off0] = ((uint32_t)row << 6) | (uint32_t)bit;
    off0++;
  }
  if (b == CBLK - 1) {
    ws->tgt[0][t] = (uint32_t)t;
    ws->tgt[1][t] = (uint32_t)t;
    if (t == 0) {
      uint32_t total = exclS + mySum;
      uint32_t P = total < (uint32_t)TCAP ? total : (uint32_t)TCAP;
      uint32_t M = NM_TOT - P;
      uint32_t npos = P < 128u ? P : 128u;
      ws->P = P; ws->M = M;
      ws->n_pos = npos; ws->n_neg = 256u - npos;
      ws->S[0] = P; ws->S[1] = M;
      ws->kcnt[0] = npos; ws->kcnt[1] = 256u - npos;
      const double LOGU = 22.18070977791825;  // log(2^32 - 1)
      for (int d = 0; d < 2; ++d) {
        uint32_t Sd = ws->S[d];
        int R = 0;
        if (Sd > 1u) {
          R = (int)ceil(3.0 * log((double)Sd) / LOGU);
          if (R < 1) R = 1;
          if (R > 3) R = 3;
        }
        ws->R[d] = (uint32_t)R;
        uint32_t ck0, ck1;
        { uint32_t a = 0u, bb = (uint32_t)d; tf2(0u, 42u, a, bb); ck0 = a; ck1 = bb; }
        for (int rr = 0; rr < 3; ++rr) {
          uint32_t s0 = 0u, s1 = 1u; tf2(ck0, ck1, s0, s1);
          ws->sub[d][rr][0] = s0; ws->sub[d][rr][1] = s1;
          uint32_t n0 = 0u, n1 = 0u; tf2(ck0, ck1, n0, n1);
          ck0 = n0; ck1 = n1;
        }
      }
    }
  }
}

// Entire pos chain in one block: per round, LDS hist -> scan -> target
// mapping + bin dedup -> gather (cap 32/bin) -> rank-select. P in [64,65536].
__global__ __launch_bounds__(1024) void k_pos(WS* ws) {
  __shared__ uint32_t h8[NBINS];        // hist -> exclusive cum
  __shared__ uint32_t part[1024];
  __shared__ int32_t  bsl[NBINS];
  __shared__ ull      sbuf[128][POSCAP];
  __shared__ uint32_t scntL[128];
  __shared__ uint32_t tg[256], tlo[256], tsl[256];
  __shared__ uint32_t nsl;
  int t = threadIdx.x;
  int R = (int)ws->R[0];
  uint32_t P = ws->P;
  uint32_t k = ws->kcnt[0];
  if (R < 1) return;                    // identity permutation
  if (t < 256) tg[t] = (uint32_t)t;
  __syncthreads();
  for (int r = R; r >= 1; --r) {
    uint32_t sk0 = ws->sub[0][r - 1][0], sk1 = ws->sub[0][r - 1][1];
    // hist
    for (int i = t; i < NBINS; i += 1024) h8[i] = 0u;
    __syncthreads();
    for (uint32_t j = t; j < P; j += 1024)
      atomicAdd(&h8[tf_bits(sk0, sk1, j) >> BINSHIFT], 1u);
    __syncthreads();
    // scan 8192 -> exclusive prefix in place
    uint32_t lv[NBINS / 1024];
    uint32_t s = 0;
    uint32_t base = (uint32_t)t * (NBINS / 1024);
#pragma unroll
    for (int e = 0; e < NBINS / 1024; ++e) { lv[e] = h8[base + e]; s += lv[e]; }
    part[t] = s;
    __syncthreads();
    for (int off = 1; off < 1024; off <<= 1) {
      uint32_t add = (t >= off) ? part[t - off] : 0u;
      __syncthreads();
      part[t] += add;
      __syncthreads();
    }
    uint32_t run = part[t] - s;
#pragma unroll
    for (int e = 0; e < NBINS / 1024; ++e) { h8[base + e] = run; run += lv[e]; }
    // dedup
    for (int i = t; i < NBINS; i += 1024) bsl[i] = -1;
    if (t == 0) nsl = 0u;
    if (t < 128) scntL[t] = 0u;
    __syncthreads();
    uint32_t lo = 0; int old = 0;
    if (t < (int)k) {
      uint32_t tr = tg[t];
      uint32_t hi = NBINS;
      while (hi - lo > 1u) {
        uint32_t mid = (lo + hi) >> 1;
        if (h8[mid] <= tr) lo = mid; else hi = mid;
      }
      tlo[t] = tr - h8[lo];
      old = atomicCAS(&bsl[lo], -1, (int)(0x10000u + (uint32_t)t));
    }
    __syncthreads();
    if (t < (int)k && old == -1) {
      uint32_t sl = atomicAdd(&nsl, 1u);
      bsl[lo] = (int)sl;
    }
    __syncthreads();
    if (t < (int)k) tsl[t] = (uint32_t)bsl[lo];
    __syncthreads();
    // gather (second threefry pass)
    for (uint32_t j = t; j < P; j += 1024) {
      uint32_t kk = tf_bits(sk0, sk1, j);
      int sl = bsl[kk >> BINSHIFT];
      if (sl >= 0) {
        uint32_t idx = atomicAdd(&scntL[sl], 1u);
        if (idx < POSCAP) sbuf[sl][idx] = ((ull)kk << 24) | (ull)j;
      }
    }
    __syncthreads();
    // select
    if (t < (int)k) {
      uint32_t sl = tsl[t], r2 = tlo[t];
      uint32_t cn = scntL[sl] < POSCAP ? scntL[sl] : POSCAP;
      for (uint32_t x = 0; x < cn; ++x) {
        ull vx = sbuf[sl][x];
        uint32_t rank = 0;
        for (uint32_t y = 0; y < cn; ++y) rank += (sbuf[sl][y] < vx) ? 1u : 0u;
        if (rank == r2) { tg[t] = (uint32_t)(vx & 0xFFFFFFull); break; }
      }
    }
    __syncthreads();
  }
  if (t < (int)k) ws->tgt[0][t] = tg[t];
}

// All 3 neg-round hists + u16 bin-id caches in one kernel (hist3 pre-zeroed).
__global__ __launch_bounds__(1024) void k_hist3(WS* ws) {
  __shared__ uint32_t lh[NBINS];
  uint32_t S = ws->M;
  uint32_t stride = gridDim.x * blockDim.x;
  for (int mm = 0; mm < 3; ++mm) {
    uint32_t sk0 = ws->sub[1][2 - mm][0], sk1 = ws->sub[1][2 - mm][1];
    uint16_t* bid = ws->binid3[mm];
    for (int i = threadIdx.x; i < NBINS; i += blockDim.x) lh[i] = 0u;
    __syncthreads();
    uint32_t j = blockIdx.x * blockDim.x + threadIdx.x;
    for (; j + stride < S; j += 2 * stride) {
      uint32_t k0 = tf_bits(sk0, sk1, j);
      uint32_t k1 = tf_bits(sk0, sk1, j + stride);
      bid[j] = (uint16_t)(k0 >> BINSHIFT);
      bid[j + stride] = (uint16_t)(k1 >> BINSHIFT);
      atomicAdd(&lh[k0 >> BINSHIFT], 1u);
      atomicAdd(&lh[k1 >> BINSHIFT], 1u);
    }
    if (j < S) {
      uint32_t k0 = tf_bits(sk0, sk1, j);
      bid[j] = (uint16_t)(k0 >> BINSHIFT);
      atomicAdd(&lh[k0 >> BINSHIFT], 1u);
    }
    __syncthreads();
    for (int i = threadIdx.x; i < NBINS; i += blockDim.x) {
      uint32_t v = lh[i];
      if (v) atomicAdd(&ws->hist3[mm][i], v);
    }
    __syncthreads();
  }
}

// scanloc body (1024 threads): LDS scan of hist3[m], per-target binary
// search, LDS bin dedup; writes full binslot map + zeroes slotCnt/nslots.
__device__ void scanloc_body(WS* ws, int m, uint32_t* cumS, uint32_t* part,
                             int32_t* bslL, uint32_t* nslL) {
  int t = threadIdx.x;
  const int E = NBINS / 1024;
  uint32_t lv[E];
  uint32_t s = 0;
  uint32_t base = (uint32_t)t * E;
#pragma unroll
  for (int e = 0; e < E; ++e) { lv[e] = ws->hist3[m][base + e]; s += lv[e]; }
  part[t] = s;
  for (int i = t; i < NBINS; i += 1024) bslL[i] = -1;
  if (t == 0) *nslL = 0u;
  __syncthreads();
  for (int off = 1; off < 1024; off <<= 1) {
    uint32_t add = (t >= off) ? part[t - off] : 0u;
    __syncthreads();
    part[t] += add;
    __syncthreads();
  }
  uint32_t run = part[t] - s;
#pragma unroll
  for (int e = 0; e < E; ++e) { cumS[base + e] = run; run += lv[e]; }
  if (t == 1023) cumS[NBINS] = run;
  __syncthreads();
  uint32_t k = ws->kcnt[1];
  uint32_t lo = 0; int old = 0;
  if (t < (int)k) {
    uint32_t tr = ws->tgt[1][t];
    uint32_t hi = NBINS;
    while (hi - lo > 1u) {
      uint32_t mid = (lo + hi) >> 1;
      if (cumS[mid] <= tr) lo = mid; else hi = mid;
    }
    ws->tlocal[t] = tr - cumS[lo];
    old = atomicCAS(&bslL[lo], -1, (int)(0x10000u + (uint32_t)t));
  }
  __syncthreads();
  if (t < (int)k && old == -1) {
    uint32_t sl = atomicAdd(nslL, 1u);
    bslL[lo] = (int)sl;
  }
  __syncthreads();
  if (t < (int)k) ws->tslot[t] = (uint32_t)bslL[lo];
  for (int i = t; i < NBINS; i += 1024) ws->binslot[i] = bslL[i];
  if (t < MAXSLOT) ws->slotCnt[t] = 0u;
  if (t == 0) ws->nslots = *nslL;
}

__global__ __launch_bounds__(1024) void k_scanloc0(WS* ws) {
  __shared__ uint32_t cumS[NBINS + 1];
  __shared__ uint32_t part[1024];
  __shared__ int32_t  bslL[NBINS];
  __shared__ uint32_t nslL;
  scanloc_body(ws, 0, cumS, part, bslL, &nslL);
}

// binid scan -> LDS compaction -> threefry for hits only -> range-reserved
// slotBuf writes.
__global__ __launch_bounds__(1024) void k_gather(WS* ws, int m) {
  __shared__ int bs[NBINS];
  __shared__ uint32_t hk[HCAP];
  __shared__ uint32_t hj[HCAP];
  __shared__ uint32_t scnt[MAXSLOT];
  __shared__ uint32_t sbase_[MAXSLOT];
  __shared__ uint32_t scur[MAXSLOT];
  __shared__ uint32_t hcnt;
  int t = threadIdx.x;
  for (int i = t; i < NBINS; i += blockDim.x) bs[i] = ws->binslot[i];
  if (t < MAXSLOT) scnt[t] = 0u;
  if (t == 0) hcnt = 0u;
  __syncthreads();
  uint32_t S = ws->M;
  uint32_t sk0 = ws->sub[1][2 - m][0], sk1 = ws->sub[1][2 - m][1];
  const uint16_t* bid = ws->binid3[m];
  uint32_t stride = gridDim.x * blockDim.x;
  for (uint32_t j = blockIdx.x * blockDim.x + t; j < S; j += stride) {
    int sl = bs[bid[j]];
    if (sl >= 0) {
      uint32_t h = atomicAdd(&hcnt, 1u);
      if (h < HCAP) {
        hj[h] = j;
      } else {
        uint32_t kk = tf_bits(sk0, sk1, j);
        uint32_t idx = atomicAdd(&ws->slotCnt[sl], 1u);
        if (idx < SLOTCAP) ws->slotBuf[sl][idx] = ((ull)kk << 24) | (ull)j;
      }
    }
  }
  __syncthreads();
  uint32_t n = hcnt < (uint32_t)HCAP ? hcnt : (uint32_t)HCAP;
  for (uint32_t h = t; h < n; h += blockDim.x) {
    uint32_t kk = tf_bits(sk0, sk1, hj[h]);
    hk[h] = kk;
    atomicAdd(&scnt[bs[kk >> BINSHIFT]], 1u);
  }
  __syncthreads();
  if (t < MAXSLOT) {
    scur[t] = 0u;
    if (scnt[t]) sbase_[t] = atomicAdd(&ws->slotCnt[t], scnt[t]);
  }
  __syncthreads();
  for (uint32_t h = t; h < n; h += blockDim.x) {
    uint32_t kk = hk[h], j = hj[h];
    int sl = bs[kk >> BINSHIFT];
    uint32_t idx = sbase_[sl] + atomicAdd(&scur[sl], 1u);
    if (idx < SLOTCAP) ws->slotBuf[sl][idx] = ((ull)kk << 24) | (ull)j;
  }
}

// Counting-sort select for slot=blockIdx.x; if doNext, last-finishing block
// runs scanloc for round m+1 (tgt writes fenced before the done counter).
__global__ __launch_bounds__(1024) void k_selscan(WS* ws, int m, int doNext) {
  __shared__ ull      srt[SLOTCAP];
  __shared__ uint32_t hh[256];
  __shared__ uint32_t cum[257];
  __shared__ uint32_t cur[256];
  __shared__ uint32_t sb[256];
  __shared__ uint32_t cumS[NBINS + 1];
  __shared__ uint32_t part[1024];
  __shared__ int32_t  bslL[NBINS];
  __shared__ uint32_t nslL;
  __shared__ uint32_t lastF;
  int t = threadIdx.x;
  int slot = blockIdx.x;
  uint32_t nslots = ws->nslots;
  if ((uint32_t)slot < nslots) {
    uint32_t cnt = ws->slotCnt[slot];
    if (cnt > SLOTCAP) cnt = SLOTCAP;
    if (t < 256) hh[t] = 0u;
    __syncthreads();
    for (uint32_t i = t; i < cnt; i += 1024) {
      ull v = ws->slotBuf[slot][i];
      atomicAdd(&hh[(uint32_t)(v >> 35) & 255u], 1u);
    }
    __syncthreads();
    if (t < 256) sb[t] = hh[t];
    __syncthreads();
    for (int off = 1; off < 256; off <<= 1) {
      uint32_t add = (t >= off && t < 256) ? sb[t - off] : 0u;
      __syncthreads();
      if (t < 256) sb[t] += add;
      __syncthreads();
    }
    if (t == 0) cum[0] = 0u;
    if (t < 256) { cum[t + 1] = sb[t]; cur[t] = 0u; }
    __syncthreads();
    for (uint32_t i = t; i < cnt; i += 1024) {
      ull v = ws->slotBuf[slot][i];
      uint32_t b = (uint32_t)(v >> 35) & 255u;
      uint32_t idx = cum[b] + atomicAdd(&cur[b], 1u);
      srt[idx] = v;
    }
    __syncthreads();
    uint32_t k = ws->kcnt[1];
    if (t < (int)k && ws->tslot[t] == (uint32_t)slot) {
      uint32_t tr = ws->tlocal[t];
      uint32_t lo = 0, hi = 256;
      while (hi - lo > 1u) {
        uint32_t mid = (lo + hi) >> 1;
        if (cum[mid] <= tr) lo = mid; else hi = mid;
      }
      uint32_t r2 = tr - cum[lo];
      uint32_t b0 = cum[lo], b1 = cum[lo + 1];
      for (uint32_t x = b0; x < b1; ++x) {
        ull vx = srt[x];
        uint32_t rank = 0;
        for (uint32_t y = b0; y < b1; ++y) rank += (srt[y] < vx) ? 1u : 0u;
        if (rank == r2) { ws->tgt[1][t] = (uint32_t)(vx & 0xFFFFFFull); break; }
      }
    }
  }
  if (doNext) {
    __threadfence();
    if (t == 0)
      lastF = (atomicAdd(&ws->selDone[m], 1u) == (uint32_t)(gridDim.x - 1)) ? 1u : 0u;
    __syncthreads();
    if (lastF) scanloc_body(ws, m + 1, cumS, part, bslL, &nslL);
  }
}

__device__ __forceinline__ float sl1(float dd) {
  float ad = fabsf(dd);
  return (ad < 1.0f) ? 0.5f * dd * dd : ad - 0.5f;
}

__global__ __launch_bounds__(256) void k_loss(WS* ws,
                                              const float* __restrict__ reg,
                                              const float* __restrict__ obj,
                                              const float4* __restrict__ tgtb,
                                              const float4* __restrict__ anch,
                                              float* out) {
  int s = threadIdx.x;
  uint32_t npos = ws->n_pos;
  double lr = 0.0, bc = 0.0;
  if (s < (int)npos) {
    uint32_t v = ws->tgt[0][s];
    uint32_t pa = ws->T[v];
    uint32_t i = pa >> 6, j = pa & 63u;
    float4 t = tgtb[j];
    float tcx = (t.x + t.z) * 0.5f, tcy = (t.y + t.w) * 0.5f;
    float tw = t.z - t.x, th = t.w - t.y;
    float4 a = anch[i];
    float r0 = (tcx - a.x) / a.z;
    float r1 = (tcy - a.y) / a.w;
    float r2 = logf(tw / a.z);
    float r3 = logf(th / a.w);
    lr = (double)sl1(reg[i * 4 + 0] - r0) + (double)sl1(reg[i * 4 + 1] - r1) +
         (double)sl1(reg[i * 4 + 2] - r2) + (double)sl1(reg[i * 4 + 3] - r3);
    float x = obj[i];
    bc = (double)(fmaxf(x, 0.0f) - x + log1pf(expf(-fabsf(x))));
  } else {
    uint32_t e = ws->tgt[1][s - (int)npos];
    uint32_t P = ws->P;
    // f = e + s0 where s0 = first q with T[q] - q > e (monotone predicate)
    uint32_t lo = 0, hi = P;
    while (lo < hi) {
      uint32_t mid = (lo + hi) >> 1;
      if (ws->T[mid] - mid > e) hi = mid; else lo = mid + 1;
    }
    uint32_t f = e + lo;
    uint32_t i = f >> 6;
    float x = obj[i];
    bc = (double)(fmaxf(x, 0.0f) + log1pf(expf(-fabsf(x))));
  }
  __shared__ double sA[256], sB[256];
  sA[s] = lr; sB[s] = bc;
  __syncthreads();
  for (int off = 128; off > 0; off >>= 1) {
    if (s < off) { sA[s] += sA[s + off]; sB[s] += sB[s + off]; }
    __syncthreads();
  }
  if (s == 0)
    out[0] = (float)(sA[0] * (10.0 / 2500.0) + sB[0] * (1.0 / 256.0));
}

extern "C" void kernel_launch(void* const* d_in, const int* in_sizes, int n_in,
                              void* d_out, int out_size, void* d_ws,
                              size_t ws_size, hipStream_t stream) {
  const float*  reg  = (const float*)d_in[0];
  const float*  obj  = (const float*)d_in[1];
  const float4* pred = (const float4*)d_in[2];
  const float4* tgtb = (const float4*)d_in[3];
  const float4* anch = (const float4*)d_in[4];
  float* out = (float*)d_out;
  WS* ws = (WS*)d_ws;
  (void)in_sizes; (void)n_in; (void)out_size; (void)ws_size;

  hipMemsetAsync(d_ws, 0, ZBYTES, stream);   // ctrl flags + lookback + hist3
  k_iou<<<CBLK, 256, 0, stream>>>(pred, tgtb, ws);
  k_scan_emit<<<CBLK, 256, 0, stream>>>(ws);
  k_pos<<<1, 1024, 0, stream>>>(ws);
  k_hist3<<<256, 1024, 0, stream>>>(ws);
  k_scanloc0<<<1, 1024, 0, stream>>>(ws);
  for (int m = 0; m < 3; ++m) {
    k_gather<<<256, 1024, 0, stream>>>(ws, m);
    k_selscan<<<MAXSLOT, 1024, 0, stream>>>(ws, m, (m < 2) ? 1 : 0);
  }
  k_loss<<<1, 256, 0, stream>>>(ws, reg, obj, tgtb, anch, out);
}